// Round 10
// baseline (262.932 us; speedup 1.0000x reference)
//
#include <hip/hip_runtime.h>
#include <hip/hip_bf16.h>
#include <cstdint>

#define S_LEN 1024
#define DMODEL 1024
#define NHEADS 16
#define DHEAD 64
#define MAXLEN 16384
#define BATCH 4

typedef __attribute__((ext_vector_type(8))) short bf16x8;
typedef __attribute__((ext_vector_type(4))) float f32x4;

// RNE f32 -> bf16 bits
__device__ inline unsigned short f2b(float f) {
  unsigned int u = __float_as_uint(f);
  unsigned int r = (u + 0x7FFFu + ((u >> 16) & 1u)) >> 16;
  return (unsigned short)r;
}
__device__ inline float b2f(unsigned short u) {
  return __uint_as_float(((unsigned int)u) << 16);
}

// Swizzled LDS element index for [R][64] bf16 rows (128B): 8 slots of 16B, slot ^= row&7.
#define LDSWZ(row, slot) (((row) << 6) + (((slot) ^ ((row) & 7)) << 3))

// ---------------- W transpose+convert x3: WT[n][k] bf16 = W[k][n] f32
__global__ __launch_bounds__(256) void wt_convert3(
    const float* __restrict__ W0, const float* __restrict__ W1, const float* __restrict__ W2,
    unsigned short* __restrict__ T0, unsigned short* __restrict__ T1, unsigned short* __restrict__ T2) {
  const float* W = (blockIdx.z == 0) ? W0 : (blockIdx.z == 1) ? W1 : W2;
  unsigned short* WT = (blockIdx.z == 0) ? T0 : (blockIdx.z == 1) ? T1 : T2;
  __shared__ float t[32][33];
  const int bi = blockIdx.y * 32, bj = blockIdx.x * 32;
  const int r = threadIdx.x >> 3, c4 = (threadIdx.x & 7) * 4;
  float4 f = *(const float4*)&W[(size_t)(bi + r) * DMODEL + bj + c4];
  t[r][c4] = f.x; t[r][c4 + 1] = f.y; t[r][c4 + 2] = f.z; t[r][c4 + 3] = f.w;
  __syncthreads();
  ushort4 u;
  u.x = f2b(t[c4][r]); u.y = f2b(t[c4 + 1][r]);
  u.z = f2b(t[c4 + 2][r]); u.w = f2b(t[c4 + 3][r]);
  *(ushort4*)&WT[(size_t)(bj + r) * DMODEL + bi + c4] = u;
}

// ---------------- Er slice convert: Erb[c][d] = bf16(Er[MAXLEN-S+c][d])
__global__ __launch_bounds__(256) void er_convert(const float* __restrict__ Er,
                                                  unsigned short* __restrict__ Erb) {
  const int i = blockIdx.x * 1024 + threadIdx.x * 4;
  float4 f = *(const float4*)(Er + (size_t)(MAXLEN - S_LEN) * DHEAD + i);
  Erb[i] = f2b(f.x); Erb[i + 1] = f2b(f.y); Erb[i + 2] = f2b(f.z); Erb[i + 3] = f2b(f.w);
}

// ---------------- Projections (z selects q/k/v): Out(bf16) = X@W + b
__global__ __launch_bounds__(256) void proj_mfma3(
    const float* __restrict__ X0, const float* __restrict__ X1, const float* __restrict__ X2,
    const unsigned short* __restrict__ T0, const unsigned short* __restrict__ T1,
    const unsigned short* __restrict__ T2,
    const float* __restrict__ b0, const float* __restrict__ b1, const float* __restrict__ b2,
    unsigned short* __restrict__ O0, unsigned short* __restrict__ O1,
    unsigned short* __restrict__ O2) {
  const int z = blockIdx.z;
  const float* X = (z == 0) ? X0 : (z == 1) ? X1 : X2;
  const unsigned short* WT = (z == 0) ? T0 : (z == 1) ? T1 : T2;
  const float* bias = (z == 0) ? b0 : (z == 1) ? b1 : b2;
  unsigned short* Out = (z == 0) ? O0 : (z == 1) ? O1 : O2;
  __shared__ unsigned short As[128 * 64];
  __shared__ unsigned short Bs[128 * 64];
  const int tid = threadIdx.x;
  const int l = tid & 63, wid = tid >> 6;
  const int bm = blockIdx.y * 128, bn = blockIdx.x * 128;
  const int wr = (wid >> 1) * 64, wc = (wid & 1) * 64;
  f32x4 acc[4][4] = {};
  for (int k0 = 0; k0 < DMODEL; k0 += 64) {
    __syncthreads();
#pragma unroll
    for (int r = 0; r < 4; ++r) {
      int s = r * 256 + tid;
      int row = s >> 3, sl = s & 7;
      const float* src = X + (size_t)(bm + row) * DMODEL + k0 + sl * 8;
      float4 f0 = *(const float4*)src;
      float4 f1 = *(const float4*)(src + 4);
      union { unsigned short h[8]; int4 v; } u;
      u.h[0] = f2b(f0.x); u.h[1] = f2b(f0.y); u.h[2] = f2b(f0.z); u.h[3] = f2b(f0.w);
      u.h[4] = f2b(f1.x); u.h[5] = f2b(f1.y); u.h[6] = f2b(f1.z); u.h[7] = f2b(f1.w);
      *(int4*)&As[LDSWZ(row, sl)] = u.v;
    }
#pragma unroll
    for (int r = 0; r < 4; ++r) {
      int s = r * 256 + tid;
      int row = s >> 3, sl = s & 7;
      int4 v = *(const int4*)(WT + (size_t)(bn + row) * DMODEL + k0 + sl * 8);
      *(int4*)&Bs[LDSWZ(row, sl)] = v;
    }
    __syncthreads();
#pragma unroll
    for (int ks = 0; ks < 2; ++ks) {
      bf16x8 a[4], b[4];
#pragma unroll
      for (int f = 0; f < 4; ++f) {
        int row = wr + f * 16 + (l & 15);
        a[f] = *(const bf16x8*)&As[LDSWZ(row, ks * 4 + (l >> 4))];
        int col = wc + f * 16 + (l & 15);
        b[f] = *(const bf16x8*)&Bs[LDSWZ(col, ks * 4 + (l >> 4))];
      }
#pragma unroll
      for (int i = 0; i < 4; ++i)
#pragma unroll
        for (int j = 0; j < 4; ++j)
          acc[i][j] = __builtin_amdgcn_mfma_f32_16x16x32_bf16(a[i], b[j], acc[i][j], 0, 0, 0);
    }
  }
#pragma unroll
  for (int i = 0; i < 4; ++i) {
    int m = bm + wr + i * 16 + ((l >> 4) << 2);
#pragma unroll
    for (int j = 0; j < 4; ++j) {
      int n = bn + wc + j * 16 + (l & 15);
      float bv = bias[n];
#pragma unroll
      for (int e = 0; e < 4; ++e)
        Out[(size_t)(m + e) * DMODEL + n] = f2b(acc[i][j][e] + bv);
    }
  }
}

// ---------------- Fused attention with on-the-fly rel band (no G matrix at all).
// band[rho][col] = q[s0+rho] . Er_sl[(c00 + ti*64 + col) mod 1024], col in [0,128).
// rel(s,t) = band[r2][ j - r2 + 64 ] with r2 = r + (d>=2), r=s-s0, j=t-t0, d=t-s; 0 at d==1.
// Matching both skew branches requires c00 = (959 - s0) mod 1024  [d<=0 -> scol=1023+d; d>=2 -> scol=d-2].
// Er window slides +64/tile -> circular mod-128-slot LDS buffer. Band pipelined 1 tile ahead.
// 3 barriers/tile: [A] commit K/V/Er-half | [B] QK + band(ti+1) + rel(ti)+softmax | [C] band write + PV.
__global__ __launch_bounds__(256) void attn_band(
    const unsigned short* __restrict__ qp, const unsigned short* __restrict__ kp,
    const unsigned short* __restrict__ vp, const unsigned short* __restrict__ erb,
    float* __restrict__ out) {
  // XCD-aware bijection over 1024 blocks: all 16 s-blocks of a bh share an XCD.
  const int o = blockIdx.y * 16 + blockIdx.x;
  const int lid = (o & 7) * 128 + (o >> 3);
  const int s0 = (lid & 15) * 64;
  const int bh = lid >> 4;
  const int b = bh >> 4, h = bh & 15;

  __shared__ unsigned short lds[29184];  // 58368 B -> 2 blocks/CU
  const int KS = 0;        // K tile 64x64
  const int VT = 4096;     // V^T tile 64x64 (pair-packed)
  const int ER = 8192;     // Er circular window: 128 slots x 64 d (slot = scol & 127)
  const int BD = 16384;    // band 65 x 132 (padded rows)
  const int PP = 25088;    // Q staging (prologue), then 4x per-wave P strips

  const int tid = threadIdx.x, l = tid & 63, w = tid >> 6;
  const int lg = l >> 4, li = l & 15;
  const unsigned short* qb = qp + (size_t)b * S_LEN * DMODEL + h * DHEAD;
  const unsigned short* kb = kp + (size_t)b * S_LEN * DMODEL + h * DHEAD;
  const unsigned short* vb = vp + (size_t)b * S_LEN * DMODEL + h * DHEAD;
  const int pr = tid & 31, dh0 = (tid >> 5) * 8;
  const int c00 = (959 - s0 + 1024) & 1023;  // FIXED: was 1023-s0 (off by +64)

  // ---- prologue: load Q, Qx(rows s0+64..79, clamped), Er window(0), K(0), V(0)
  int4 qpr[2];
#pragma unroll
  for (int r = 0; r < 2; ++r) {
    int s = r * 256 + tid; int row = s >> 3, sl = s & 7;
    qpr[r] = *(const int4*)(qb + (size_t)(s0 + row) * DMODEL + sl * 8);
  }
  int4 qxr;
  {
    int row = (tid & 127) >> 3, sl = tid & 7;
    int srcr = s0 + 64 + row; if (srcr > S_LEN - 1) srcr = S_LEN - 1;
    qxr = *(const int4*)(qb + (size_t)srcr * DMODEL + sl * 8);
  }
  int4 er0[4];
#pragma unroll
  for (int r = 0; r < 4; ++r) {
    int s = r * 256 + tid; int k = s >> 3, sl = s & 7;
    int scol = (c00 + k) & 1023;
    er0[r] = *(const int4*)(erb + (size_t)scol * DHEAD + sl * 8);
  }
  int4 kpr[2]; int4 vpr0, vpr1;
#pragma unroll
  for (int r = 0; r < 2; ++r) {
    int s = r * 256 + tid; int row = s >> 3, sl = s & 7;
    kpr[r] = *(const int4*)(kb + (size_t)row * DMODEL + sl * 8);
  }
  vpr0 = *(const int4*)(vb + (size_t)(pr * 2) * DMODEL + dh0);
  vpr1 = *(const int4*)(vb + (size_t)(pr * 2 + 1) * DMODEL + dh0);

  // commit Q -> PP, Qx -> BD (temp), Er window(0) -> ER
#pragma unroll
  for (int r = 0; r < 2; ++r) {
    int s = r * 256 + tid; int row = s >> 3, sl = s & 7;
    *(int4*)&lds[PP + LDSWZ(row, sl)] = qpr[r];
  }
  if (tid < 128) {
    int row = tid >> 3, sl = tid & 7;
    *(int4*)&lds[BD + LDSWZ(row, sl)] = qxr;
  }
#pragma unroll
  for (int r = 0; r < 4; ++r) {
    int s = r * 256 + tid; int k = s >> 3, sl = s & 7;
    int slot = (c00 + k) & 127;
    *(int4*)&lds[ER + LDSWZ(slot, sl)] = er0[r];
  }
  __syncthreads();
  // read Q fragments; band(0) MFMA; issue Er half for window(1)
  bf16x8 qf[2], qx[2];
#pragma unroll
  for (int ks = 0; ks < 2; ++ks)
    qf[ks] = *(const bf16x8*)&lds[PP + LDSWZ(w * 16 + li, ks * 4 + lg)];
  if (w == 3) {
#pragma unroll
    for (int ks = 0; ks < 2; ++ks)
      qx[ks] = *(const bf16x8*)&lds[BD + LDSWZ(li, ks * 4 + lg)];
  }
  f32x4 g[8] = {}; f32x4 gx[4] = {};
#pragma unroll
  for (int ks = 0; ks < 2; ++ks)
#pragma unroll
    for (int f2 = 0; f2 < 8; ++f2) {
      int slot = (c00 + f2 * 16 + li) & 127;
      bf16x8 ef = *(const bf16x8*)&lds[ER + LDSWZ(slot, ks * 4 + lg)];
      g[f2] = __builtin_amdgcn_mfma_f32_16x16x32_bf16(qf[ks], ef, g[f2], 0, 0, 0);
      if (f2 < 4 && w == 3)
        gx[f2] = __builtin_amdgcn_mfma_f32_16x16x32_bf16(qx[ks], ef, gx[f2], 0, 0, 0);
    }
  int4 epr[2];
#pragma unroll
  for (int r = 0; r < 2; ++r) {
    int s = r * 256 + tid; int k = s >> 3, sl = s & 7;
    int scol = (c00 + 128 + k) & 1023;
    epr[r] = *(const int4*)(erb + (size_t)scol * DHEAD + sl * 8);
  }
  __syncthreads();
  // write band(0) (overwrites Qx staging)
#pragma unroll
  for (int f2 = 0; f2 < 8; ++f2)
#pragma unroll
    for (int e = 0; e < 4; ++e)
      lds[BD + (w * 16 + lg * 4 + e) * 132 + f2 * 16 + li] = f2b(g[f2][e]);
  if (w == 3 && lg == 0) {
#pragma unroll
    for (int f2 = 0; f2 < 4; ++f2)
      lds[BD + 64 * 132 + f2 * 16 + li] = f2b(gx[f2][0]);
  }

  f32x4 o4[4] = {};
  float m_r[4] = {-1e30f, -1e30f, -1e30f, -1e30f};
  float l_r[4] = {0.f, 0.f, 0.f, 0.f};
  int rr[4];
#pragma unroll
  for (int i = 0; i < 4; ++i) rr[i] = w * 16 + (lg << 2) + i;

  for (int ti = 0; ti < 16; ++ti) {
    const int t0 = ti * 64;
    __syncthreads();  // BAR A: prev-iter readers done
    // ---- ph1: commits (Er half completing window(ti+1); K(ti); V(ti))
    if (ti < 15) {
#pragma unroll
      for (int r = 0; r < 2; ++r) {
        int s = r * 256 + tid; int k = s >> 3, sl = s & 7;
        int slot = (c00 + ti * 64 + k) & 127;  // = (c0(ti)+128+k) & 127
        *(int4*)&lds[ER + LDSWZ(slot, sl)] = epr[r];
      }
    }
#pragma unroll
    for (int r = 0; r < 2; ++r) {
      int s = r * 256 + tid; int row = s >> 3, sl = s & 7;
      *(int4*)&lds[KS + LDSWZ(row, sl)] = kpr[r];
    }
    {
      union { int4 v; unsigned short hh[8]; } va, vc;
      va.v = vpr0; vc.v = vpr1;
      unsigned int* vtw = (unsigned int*)(lds + VT);
#pragma unroll
      for (int j = 0; j < 8; ++j) {
        int dh = dh0 + j;
        int widx = dh * 32 + (((pr >> 2) ^ (dh & 7)) << 2) + (pr & 3);
        vtw[widx] = (unsigned int)va.hh[j] | ((unsigned int)vc.hh[j] << 16);
      }
    }
    __syncthreads();  // BAR B: staged data visible
    // ---- ph2: QK(ti)
    f32x4 sa[4] = {};
#pragma unroll
    for (int ks = 0; ks < 2; ++ks)
#pragma unroll
      for (int f = 0; f < 4; ++f) {
        bf16x8 kf = *(const bf16x8*)&lds[KS + LDSWZ(f * 16 + li, ks * 4 + lg)];
        sa[f] = __builtin_amdgcn_mfma_f32_16x16x32_bf16(qf[ks], kf, sa[f], 0, 0, 0);
      }
    // global prefetches (covered by band MFMA + rel + softmax until BAR C)
    if (ti < 15) {
      const unsigned short* kb2 = kb + (size_t)(t0 + 64) * DMODEL;
#pragma unroll
      for (int r = 0; r < 2; ++r) {
        int s = r * 256 + tid; int row = s >> 3, sl = s & 7;
        kpr[r] = *(const int4*)(kb2 + (size_t)row * DMODEL + sl * 8);
      }
      const unsigned short* vb2 = vb + (size_t)(t0 + 64 + pr * 2) * DMODEL + dh0;
      vpr0 = *(const int4*)vb2;
      vpr1 = *(const int4*)(vb2 + DMODEL);
    }
    if (ti < 14) {
#pragma unroll
      for (int r = 0; r < 2; ++r) {
        int s = r * 256 + tid; int k = s >> 3, sl = s & 7;
        int scol = (c00 + ti * 64 + 192 + k) & 1023;
        epr[r] = *(const int4*)(erb + (size_t)scol * DHEAD + sl * 8);
      }
    }
    // band(ti+1) MFMA (window(ti+1) fully staged as of BAR B)
    f32x4 gg[8] = {}; f32x4 ggx[4] = {};
    if (ti < 15) {
      const int cb = c00 + (ti + 1) * 64;
#pragma unroll
      for (int ks = 0; ks < 2; ++ks)
#pragma unroll
        for (int f2 = 0; f2 < 8; ++f2) {
          int slot = (cb + f2 * 16 + li) & 127;
          bf16x8 ef = *(const bf16x8*)&lds[ER + LDSWZ(slot, ks * 4 + lg)];
          gg[f2] = __builtin_amdgcn_mfma_f32_16x16x32_bf16(qf[ks], ef, gg[f2], 0, 0, 0);
          if (f2 < 4 && w == 3)
            ggx[f2] = __builtin_amdgcn_mfma_f32_16x16x32_bf16(qx[ks], ef, ggx[f2], 0, 0, 0);
        }
    }
    // rel(ti) from band LDS + scale + tile max
    float tmax[4] = {-1e30f, -1e30f, -1e30f, -1e30f};
#pragma unroll
    for (int f = 0; f < 4; ++f) {
#pragma unroll
      for (int i = 0; i < 4; ++i) {
        int j = f * 16 + li;
        int d = t0 - s0 + j - rr[i];
        int b2 = (d >= 2) ? 1 : 0;
        int r2 = rr[i] + b2;
        int c2 = j - r2 + 64;
        float rel = (d == 1) ? 0.f : b2f(lds[BD + r2 * 132 + c2]);
        float sv = (sa[f][i] + rel) * 0.125f;
        sa[f][i] = sv;
        tmax[i] = fmaxf(tmax[i], sv);
      }
    }
#pragma unroll
    for (int off = 8; off >= 1; off >>= 1)
#pragma unroll
      for (int i = 0; i < 4; ++i) tmax[i] = fmaxf(tmax[i], __shfl_xor(tmax[i], off));
    float scale[4];
#pragma unroll
    for (int i = 0; i < 4; ++i) {
      float mn = fmaxf(m_r[i], tmax[i]);
      scale[i] = __expf(m_r[i] - mn);
      m_r[i] = mn;
    }
    float psum[4] = {0.f, 0.f, 0.f, 0.f};
    unsigned short* Pw = lds + PP + w * 1024;
#pragma unroll
    for (int f = 0; f < 4; ++f) {
#pragma unroll
      for (int i = 0; i < 4; ++i) {
        float pv = __expf(sa[f][i] - m_r[i]);
        psum[i] += pv;
        int prow = (lg << 2) + i, pcol = f * 16 + li;
        Pw[LDSWZ(prow, pcol >> 3) + (pcol & 7)] = f2b(pv);
      }
    }
#pragma unroll
    for (int off = 8; off >= 1; off >>= 1)
#pragma unroll
      for (int i = 0; i < 4; ++i) psum[i] += __shfl_xor(psum[i], off);
#pragma unroll
    for (int i = 0; i < 4; ++i) l_r[i] = l_r[i] * scale[i] + psum[i];
#pragma unroll
    for (int f = 0; f < 4; ++f)
#pragma unroll
      for (int i = 0; i < 4; ++i) o4[f][i] *= scale[i];
    __syncthreads();  // BAR C: band reads (rel) done -> safe to overwrite band
    // ---- ph3: write band(ti+1); PV(ti)
    if (ti < 15) {
#pragma unroll
      for (int f2 = 0; f2 < 8; ++f2)
#pragma unroll
        for (int e = 0; e < 4; ++e)
          lds[BD + (w * 16 + lg * 4 + e) * 132 + f2 * 16 + li] = f2b(gg[f2][e]);
      if (w == 3 && lg == 0) {
#pragma unroll
        for (int f2 = 0; f2 < 4; ++f2)
          lds[BD + 64 * 132 + f2 * 16 + li] = f2b(ggx[f2][0]);
      }
    }
#pragma unroll
    for (int ks = 0; ks < 2; ++ks) {
      bf16x8 pf = *(const bf16x8*)&Pw[LDSWZ(li, ks * 4 + lg)];
#pragma unroll
      for (int f = 0; f < 4; ++f) {
        bf16x8 vf = *(const bf16x8*)&lds[VT + LDSWZ(f * 16 + li, ks * 4 + lg)];
        o4[f] = __builtin_amdgcn_mfma_f32_16x16x32_bf16(pf, vf, o4[f], 0, 0, 0);
      }
    }
  }
  // ---- epilogue
#pragma unroll
  for (int i = 0; i < 4; ++i) {
    float inv = 1.f / l_r[i];
    int sgg = s0 + rr[i];
#pragma unroll
    for (int f = 0; f < 4; ++f)
      out[(size_t)(b * S_LEN + sgg) * DMODEL + h * DHEAD + f * 16 + li] = o4[f][i] * inv;
  }
}

extern "C" void kernel_launch(void* const* d_in, const int* in_sizes, int n_in,
                              void* d_out, int out_size, void* d_ws, size_t ws_size,
                              hipStream_t stream) {
  (void)in_sizes; (void)n_in; (void)out_size; (void)ws_size;
  const float* q_in = (const float*)d_in[0];
  const float* k_in = (const float*)d_in[1];
  const float* v_in = (const float*)d_in[2];
  const float* Wq   = (const float*)d_in[3];
  const float* bq   = (const float*)d_in[4];
  const float* Wk   = (const float*)d_in[5];
  const float* bk   = (const float*)d_in[6];
  const float* Wv   = (const float*)d_in[7];
  const float* bv   = (const float*)d_in[8];
  const float* Er   = (const float*)d_in[9];
  float* out = (float*)d_out;

  char* ws = (char*)d_ws;
  const size_t MB = (size_t)1 << 20;
  unsigned short* wtq = (unsigned short*)(ws);            // 2 MB
  unsigned short* wtk = (unsigned short*)(ws + 2 * MB);   // 2 MB
  unsigned short* wtv = (unsigned short*)(ws + 4 * MB);   // 2 MB
  unsigned short* erb = (unsigned short*)(ws + 6 * MB);   // 128 KB
  unsigned short* qp  = (unsigned short*)(ws + 8 * MB);   // 8 MB
  unsigned short* kp  = (unsigned short*)(ws + 16 * MB);  // 8 MB
  unsigned short* vp  = (unsigned short*)(ws + 24 * MB);  // 8 MB  (32 MB total)

  dim3 blk(256);
  hipLaunchKernelGGL(wt_convert3, dim3(32, 32, 3), blk, 0, stream,
                     Wq, Wk, Wv, wtq, wtk, wtv);
  hipLaunchKernelGGL(er_convert, dim3(64), blk, 0, stream, Er, erb);

  dim3 gproj(DMODEL / 128, (BATCH * S_LEN) / 128, 3);  // (8, 32, 3)
  hipLaunchKernelGGL(proj_mfma3, gproj, blk, 0, stream,
                     q_in, k_in, v_in, wtq, wtk, wtv, bq, bk, bv, qp, kp, vp);

  dim3 gattn(S_LEN / 64, BATCH * NHEADS);  // (16, 64) = 1024 blocks
  hipLaunchKernelGGL(attn_band, gattn, blk, 0, stream, qp, kp, vp, erb, out);
}

// Round 11
// 245.730 us; speedup vs baseline: 1.0700x; 1.0700x over previous
//
#include <hip/hip_runtime.h>
#include <hip/hip_bf16.h>
#include <cstdint>

#define S_LEN 1024
#define DMODEL 1024
#define NHEADS 16
#define DHEAD 64
#define MAXLEN 16384
#define BATCH 4

typedef __attribute__((ext_vector_type(8))) short bf16x8;
typedef __attribute__((ext_vector_type(4))) float f32x4;

// LDS-only barrier: waits ds ops, does NOT drain vmcnt -> global prefetches
// survive across it. "memory" clobber pins compiler memory ordering.
#define BARRIER_LGKM() asm volatile("s_waitcnt lgkmcnt(0)\n\ts_barrier" ::: "memory")

// RNE f32 -> bf16 bits
__device__ inline unsigned short f2b(float f) {
  unsigned int u = __float_as_uint(f);
  unsigned int r = (u + 0x7FFFu + ((u >> 16) & 1u)) >> 16;
  return (unsigned short)r;
}
__device__ inline float b2f(unsigned short u) {
  return __uint_as_float(((unsigned int)u) << 16);
}

// Swizzled LDS element index for [R][64] bf16 rows (128B): 8 slots of 16B, slot ^= row&7.
#define LDSWZ(row, slot) (((row) << 6) + (((slot) ^ ((row) & 7)) << 3))

// ---------------- W transpose+convert x3: WT[n][k] bf16 = W[k][n] f32
__global__ __launch_bounds__(256) void wt_convert3(
    const float* __restrict__ W0, const float* __restrict__ W1, const float* __restrict__ W2,
    unsigned short* __restrict__ T0, unsigned short* __restrict__ T1, unsigned short* __restrict__ T2) {
  const float* W = (blockIdx.z == 0) ? W0 : (blockIdx.z == 1) ? W1 : W2;
  unsigned short* WT = (blockIdx.z == 0) ? T0 : (blockIdx.z == 1) ? T1 : T2;
  __shared__ float t[32][33];
  const int bi = blockIdx.y * 32, bj = blockIdx.x * 32;
  const int r = threadIdx.x >> 3, c4 = (threadIdx.x & 7) * 4;
  float4 f = *(const float4*)&W[(size_t)(bi + r) * DMODEL + bj + c4];
  t[r][c4] = f.x; t[r][c4 + 1] = f.y; t[r][c4 + 2] = f.z; t[r][c4 + 3] = f.w;
  __syncthreads();
  ushort4 u;
  u.x = f2b(t[c4][r]); u.y = f2b(t[c4 + 1][r]);
  u.z = f2b(t[c4 + 2][r]); u.w = f2b(t[c4 + 3][r]);
  *(ushort4*)&WT[(size_t)(bj + r) * DMODEL + bi + c4] = u;
}

// ---------------- Er slice convert: Erb[c][d] = bf16(Er[MAXLEN-S+c][d])
__global__ __launch_bounds__(256) void er_convert(const float* __restrict__ Er,
                                                  unsigned short* __restrict__ Erb) {
  const int i = blockIdx.x * 1024 + threadIdx.x * 4;
  float4 f = *(const float4*)(Er + (size_t)(MAXLEN - S_LEN) * DHEAD + i);
  Erb[i] = f2b(f.x); Erb[i + 1] = f2b(f.y); Erb[i + 2] = f2b(f.z); Erb[i + 3] = f2b(f.w);
}

// ---------------- Projections (z selects q/k/v): Out(bf16) = X@W + b
__global__ __launch_bounds__(256) void proj_mfma3(
    const float* __restrict__ X0, const float* __restrict__ X1, const float* __restrict__ X2,
    const unsigned short* __restrict__ T0, const unsigned short* __restrict__ T1,
    const unsigned short* __restrict__ T2,
    const float* __restrict__ b0, const float* __restrict__ b1, const float* __restrict__ b2,
    unsigned short* __restrict__ O0, unsigned short* __restrict__ O1,
    unsigned short* __restrict__ O2) {
  const int z = blockIdx.z;
  const float* X = (z == 0) ? X0 : (z == 1) ? X1 : X2;
  const unsigned short* WT = (z == 0) ? T0 : (z == 1) ? T1 : T2;
  const float* bias = (z == 0) ? b0 : (z == 1) ? b1 : b2;
  unsigned short* Out = (z == 0) ? O0 : (z == 1) ? O1 : O2;
  __shared__ unsigned short As[128 * 64];
  __shared__ unsigned short Bs[128 * 64];
  const int tid = threadIdx.x;
  const int l = tid & 63, wid = tid >> 6;
  const int bm = blockIdx.y * 128, bn = blockIdx.x * 128;
  const int wr = (wid >> 1) * 64, wc = (wid & 1) * 64;
  f32x4 acc[4][4] = {};
  for (int k0 = 0; k0 < DMODEL; k0 += 64) {
    __syncthreads();
#pragma unroll
    for (int r = 0; r < 4; ++r) {
      int s = r * 256 + tid;
      int row = s >> 3, sl = s & 7;
      const float* src = X + (size_t)(bm + row) * DMODEL + k0 + sl * 8;
      float4 f0 = *(const float4*)src;
      float4 f1 = *(const float4*)(src + 4);
      union { unsigned short h[8]; int4 v; } u;
      u.h[0] = f2b(f0.x); u.h[1] = f2b(f0.y); u.h[2] = f2b(f0.z); u.h[3] = f2b(f0.w);
      u.h[4] = f2b(f1.x); u.h[5] = f2b(f1.y); u.h[6] = f2b(f1.z); u.h[7] = f2b(f1.w);
      *(int4*)&As[LDSWZ(row, sl)] = u.v;
    }
#pragma unroll
    for (int r = 0; r < 4; ++r) {
      int s = r * 256 + tid;
      int row = s >> 3, sl = s & 7;
      int4 v = *(const int4*)(WT + (size_t)(bn + row) * DMODEL + k0 + sl * 8);
      *(int4*)&Bs[LDSWZ(row, sl)] = v;
    }
    __syncthreads();
#pragma unroll
    for (int ks = 0; ks < 2; ++ks) {
      bf16x8 a[4], b[4];
#pragma unroll
      for (int f = 0; f < 4; ++f) {
        int row = wr + f * 16 + (l & 15);
        a[f] = *(const bf16x8*)&As[LDSWZ(row, ks * 4 + (l >> 4))];
        int col = wc + f * 16 + (l & 15);
        b[f] = *(const bf16x8*)&Bs[LDSWZ(col, ks * 4 + (l >> 4))];
      }
#pragma unroll
      for (int i = 0; i < 4; ++i)
#pragma unroll
        for (int j = 0; j < 4; ++j)
          acc[i][j] = __builtin_amdgcn_mfma_f32_16x16x32_bf16(a[i], b[j], acc[i][j], 0, 0, 0);
    }
  }
#pragma unroll
  for (int i = 0; i < 4; ++i) {
    int m = bm + wr + i * 16 + ((l >> 4) << 2);
#pragma unroll
    for (int j = 0; j < 4; ++j) {
      int n = bn + wc + j * 16 + (l & 15);
      float bv = bias[n];
#pragma unroll
      for (int e = 0; e < 4; ++e)
        Out[(size_t)(m + e) * DMODEL + n] = f2b(acc[i][j][e] + bv);
    }
  }
}

// ---------------- QEr: G(bf16)[s][c] = q . Er[c], per (b,h). M=N=1024, K=64 single stage.
__global__ __launch_bounds__(256) void qer_mfma(const unsigned short* __restrict__ qp,
    const unsigned short* __restrict__ Erb, unsigned short* __restrict__ G, int bh0) {
  const int bh = bh0 + blockIdx.z;
  const int b = bh >> 4, h = bh & 15;
  __shared__ unsigned short As[128 * 64];
  __shared__ unsigned short Bs[128 * 64];
  const int tid = threadIdx.x, l = tid & 63, wid = tid >> 6;
  const int bm = blockIdx.y * 128, bn = blockIdx.x * 128;
  const int wr = (wid >> 1) * 64, wc = (wid & 1) * 64;
  const unsigned short* qb = qp + (size_t)b * S_LEN * DMODEL + h * DHEAD;
  unsigned short* Gc = G + (size_t)blockIdx.z * S_LEN * S_LEN;
#pragma unroll
  for (int r = 0; r < 4; ++r) {
    int s = r * 256 + tid;
    int row = s >> 3, sl = s & 7;
    *(int4*)&As[LDSWZ(row, sl)] = *(const int4*)(qb + (size_t)(bm + row) * DMODEL + sl * 8);
    *(int4*)&Bs[LDSWZ(row, sl)] = *(const int4*)(Erb + (size_t)(bn + row) * DHEAD + sl * 8);
  }
  __syncthreads();
  f32x4 acc[4][4] = {};
#pragma unroll
  for (int ks = 0; ks < 2; ++ks) {
    bf16x8 a[4], b[4];
#pragma unroll
    for (int f = 0; f < 4; ++f) {
      int row = wr + f * 16 + (l & 15);
      a[f] = *(const bf16x8*)&As[LDSWZ(row, ks * 4 + (l >> 4))];
      int col = wc + f * 16 + (l & 15);
      b[f] = *(const bf16x8*)&Bs[LDSWZ(col, ks * 4 + (l >> 4))];
    }
#pragma unroll
    for (int i = 0; i < 4; ++i)
#pragma unroll
      for (int j = 0; j < 4; ++j)
        acc[i][j] = __builtin_amdgcn_mfma_f32_16x16x32_bf16(a[i], b[j], acc[i][j], 0, 0, 0);
  }
#pragma unroll
  for (int i = 0; i < 4; ++i) {
    int m = bm + wr + i * 16 + ((l >> 4) << 2);
#pragma unroll
    for (int j = 0; j < 4; ++j) {
      int n = bn + wc + j * 16 + (l & 15);
#pragma unroll
      for (int e = 0; e < 4; ++e)
        Gc[(size_t)(m + e) * S_LEN + n] = f2b(acc[i][j][e]);
    }
  }
}

// ---------------- Fused attention. r4 structure (single K/V buffer, 2 barriers/tile) but
// barriers are LDS-only (no vmcnt drain) -> 1-tile-ahead prefetches (K/V regs + 16 rel
// gathers from G) genuinely stay in flight across barriers.
// rel flat-skew: idx = s*1023 + 1022 + tg + (d<=0); 0 at d==1. LDS 24 KB (Q/P overlaid).
__global__ __launch_bounds__(256) void attn_mfma(const unsigned short* __restrict__ qp,
    const unsigned short* __restrict__ kp, const unsigned short* __restrict__ vp,
    const unsigned short* __restrict__ G, float* __restrict__ out, int bh0) {
  const int bh = bh0 + blockIdx.y;
  const int b = bh >> 4, h = bh & 15;
  const int s0 = blockIdx.x * 64;
  __shared__ unsigned short lds[12288];  // 24576 B: K[0,4096) V^T[4096,8192) Q/P[8192,12288)
  const int KS = 0, VT = 4096, PQ = 8192;
  const int tid = threadIdx.x, l = tid & 63, w = tid >> 6;
  const int lg = l >> 4, li = l & 15;
  const unsigned short* qb = qp + (size_t)b * S_LEN * DMODEL + h * DHEAD;
  const unsigned short* kb = kp + (size_t)b * S_LEN * DMODEL + h * DHEAD;
  const unsigned short* vb = vp + (size_t)b * S_LEN * DMODEL + h * DHEAD;
  const unsigned short* Gb = G + (size_t)blockIdx.y * S_LEN * S_LEN;
  const int pr = tid & 31, dh0 = (tid >> 5) * 8;

  // ---- prologue: stage Q (each wave reads only its own 16-row strip later; P strips
  // reuse the same per-wave region -> wave-local aliasing only, no cross-wave hazard).
#pragma unroll
  for (int r = 0; r < 2; ++r) {
    int s = r * 256 + tid;
    int row = s >> 3, sl = s & 7;
    *(int4*)&lds[PQ + LDSWZ(row, sl)] = *(const int4*)(qb + (size_t)(s0 + row) * DMODEL + sl * 8);
  }
  // issue K/V tile-0 loads (consumed at first commit), then rel gathers tile-0
  int4 kpr[2];
#pragma unroll
  for (int r = 0; r < 2; ++r) {
    int s = r * 256 + tid; int row = s >> 3, sl = s & 7;
    kpr[r] = *(const int4*)(kb + (size_t)row * DMODEL + sl * 8);
  }
  int4 vpr0 = *(const int4*)(vb + (size_t)(pr * 2) * DMODEL + dh0);
  int4 vpr1 = *(const int4*)(vb + (size_t)(pr * 2 + 1) * DMODEL + dh0);
  int sg[4], pre[4];
#pragma unroll
  for (int i = 0; i < 4; ++i) {
    sg[i] = s0 + w * 16 + (lg << 2) + i;
    pre[i] = sg[i] * 1023 + 1022;
  }
  unsigned int rv[4][4];
#pragma unroll
  for (int f = 0; f < 4; ++f)
#pragma unroll
    for (int i = 0; i < 4; ++i) {
      int tg = f * 16 + li;
      rv[f][i] = Gb[pre[i] + tg + ((tg - sg[i]) <= 0 ? 1 : 0)];
    }
  BARRIER_LGKM();  // Q visible
  bf16x8 qf[2];
#pragma unroll
  for (int ks = 0; ks < 2; ++ks)
    qf[ks] = *(const bf16x8*)&lds[PQ + LDSWZ(w * 16 + li, ks * 4 + lg)];

  f32x4 o4[4] = {};
  float m_r[4] = {-1e30f, -1e30f, -1e30f, -1e30f};
  float l_r[4] = {0.f, 0.f, 0.f, 0.f};

  for (int ti = 0; ti < 16; ++ti) {
    const int t0 = ti * 64;
    BARRIER_LGKM();  // BAR_R: all waves done reading K/V(ti-1); vmcnt NOT drained
    // ---- commit K/V(ti) from regs (hw waits vmcnt for kpr/vpr here; issued last iter)
#pragma unroll
    for (int r = 0; r < 2; ++r) {
      int s = r * 256 + tid; int row = s >> 3, sl = s & 7;
      *(int4*)&lds[KS + LDSWZ(row, sl)] = kpr[r];
    }
    {
      union { int4 v; unsigned short hh[8]; } va, vc;
      va.v = vpr0; vc.v = vpr1;
      unsigned int* vtw = (unsigned int*)(lds + VT);
#pragma unroll
      for (int j = 0; j < 8; ++j) {
        int dh = dh0 + j;
        int widx = dh * 32 + (((pr >> 2) ^ (dh & 7)) << 2) + (pr & 3);
        vtw[widx] = (unsigned int)va.hh[j] | ((unsigned int)vc.hh[j] << 16);
      }
    }
    BARRIER_LGKM();  // BAR_W: K/V visible; rel gathers (rv) still in flight
    // ---- QK(ti)
    f32x4 sa[4] = {};
#pragma unroll
    for (int ks = 0; ks < 2; ++ks)
#pragma unroll
      for (int f = 0; f < 4; ++f) {
        bf16x8 kf = *(const bf16x8*)&lds[KS + LDSWZ(f * 16 + li, ks * 4 + lg)];
        sa[f] = __builtin_amdgcn_mfma_f32_16x16x32_bf16(qf[ks], kf, sa[f], 0, 0, 0);
      }
    // ---- issue K/V(ti+1) loads (in flight across both barriers, consumed next commit)
    if (ti < 15) {
      const unsigned short* kb2 = kb + (size_t)(t0 + 64) * DMODEL;
#pragma unroll
      for (int r = 0; r < 2; ++r) {
        int s = r * 256 + tid; int row = s >> 3, sl = s & 7;
        kpr[r] = *(const int4*)(kb2 + (size_t)row * DMODEL + sl * 8);
      }
      const unsigned short* vb2 = vb + (size_t)(t0 + 64 + pr * 2) * DMODEL + dh0;
      vpr0 = *(const int4*)vb2;
      vpr1 = *(const int4*)(vb2 + DMODEL);
    }
    // ---- apply rel (rv issued a full tile ago) + scale + tile max
    float tmax[4] = {-1e30f, -1e30f, -1e30f, -1e30f};
#pragma unroll
    for (int f = 0; f < 4; ++f) {
#pragma unroll
      for (int i = 0; i < 4; ++i) {
        int tg = t0 + f * 16 + li;
        int dd = tg - sg[i];
        float rel = (dd == 1) ? 0.f : b2f((unsigned short)rv[f][i]);
        float sv = (sa[f][i] + rel) * 0.125f;
        sa[f][i] = sv;
        tmax[i] = fmaxf(tmax[i], sv);
      }
    }
    // ---- issue rel gathers for ti+1 (WAR on rv regs; in flight across both barriers)
    if (ti < 15) {
      const int t0n = t0 + 64;
#pragma unroll
      for (int f = 0; f < 4; ++f)
#pragma unroll
        for (int i = 0; i < 4; ++i) {
          int tg = t0n + f * 16 + li;
          rv[f][i] = Gb[pre[i] + tg + ((tg - sg[i]) <= 0 ? 1 : 0)];
        }
    }
    // ---- online softmax
#pragma unroll
    for (int off = 8; off >= 1; off >>= 1)
#pragma unroll
      for (int i = 0; i < 4; ++i) tmax[i] = fmaxf(tmax[i], __shfl_xor(tmax[i], off));
    float scale[4];
#pragma unroll
    for (int i = 0; i < 4; ++i) {
      float mn = fmaxf(m_r[i], tmax[i]);
      scale[i] = __expf(m_r[i] - mn);
      m_r[i] = mn;
    }
    float psum[4] = {0.f, 0.f, 0.f, 0.f};
    unsigned short* Pw = lds + PQ + w * 1024;  // own strip (= own Q rows, wave-local)
#pragma unroll
    for (int f = 0; f < 4; ++f) {
#pragma unroll
      for (int i = 0; i < 4; ++i) {
        float pv = __expf(sa[f][i] - m_r[i]);
        psum[i] += pv;
        int prow = (lg << 2) + i, pcol = f * 16 + li;
        Pw[LDSWZ(prow, pcol >> 3) + (pcol & 7)] = f2b(pv);
      }
    }
#pragma unroll
    for (int off = 8; off >= 1; off >>= 1)
#pragma unroll
      for (int i = 0; i < 4; ++i) psum[i] += __shfl_xor(psum[i], off);
#pragma unroll
    for (int i = 0; i < 4; ++i) l_r[i] = l_r[i] * scale[i] + psum[i];
#pragma unroll
    for (int f = 0; f < 4; ++f)
#pragma unroll
      for (int i = 0; i < 4; ++i) o4[f][i] *= scale[i];
    // ---- PV(ti)
#pragma unroll
    for (int ks = 0; ks < 2; ++ks) {
      bf16x8 pf = *(const bf16x8*)&Pw[LDSWZ(li, ks * 4 + lg)];
#pragma unroll
      for (int f = 0; f < 4; ++f) {
        bf16x8 vf = *(const bf16x8*)&lds[VT + LDSWZ(f * 16 + li, ks * 4 + lg)];
        o4[f] = __builtin_amdgcn_mfma_f32_16x16x32_bf16(pf, vf, o4[f], 0, 0, 0);
      }
    }
  }
  // ---- epilogue
#pragma unroll
  for (int i = 0; i < 4; ++i) {
    float inv = 1.f / l_r[i];
#pragma unroll
    for (int f = 0; f < 4; ++f)
      out[(size_t)(b * S_LEN + sg[i]) * DMODEL + h * DHEAD + f * 16 + li] = o4[f][i] * inv;
  }
}

extern "C" void kernel_launch(void* const* d_in, const int* in_sizes, int n_in,
                              void* d_out, int out_size, void* d_ws, size_t ws_size,
                              hipStream_t stream) {
  (void)in_sizes; (void)n_in; (void)out_size;
  const float* q_in = (const float*)d_in[0];
  const float* k_in = (const float*)d_in[1];
  const float* v_in = (const float*)d_in[2];
  const float* Wq   = (const float*)d_in[3];
  const float* bq   = (const float*)d_in[4];
  const float* Wk   = (const float*)d_in[5];
  const float* bk   = (const float*)d_in[6];
  const float* Wv   = (const float*)d_in[7];
  const float* bv   = (const float*)d_in[8];
  const float* Er   = (const float*)d_in[9];
  float* out = (float*)d_out;

  char* ws = (char*)d_ws;
  const size_t MB = (size_t)1 << 20;
  unsigned short* wtq = (unsigned short*)(ws);            // 2 MB
  unsigned short* wtk = (unsigned short*)(ws + 2 * MB);   // 2 MB
  unsigned short* wtv = (unsigned short*)(ws + 4 * MB);   // 2 MB
  unsigned short* erb = (unsigned short*)(ws + 6 * MB);   // 128 KB
  unsigned short* qp  = (unsigned short*)(ws + 8 * MB);   // 8 MB
  unsigned short* kp  = (unsigned short*)(ws + 16 * MB);  // 8 MB
  unsigned short* vp  = (unsigned short*)(ws + 24 * MB);  // 8 MB
  unsigned short* G   = (unsigned short*)(ws + 32 * MB);  // nb * 2 MB

  const size_t gavail = (ws_size > 32 * MB) ? (ws_size - 32 * MB) : 0;
  int chunk = (int)(gavail / (2 * MB));
  if (chunk < 1) chunk = 1;
  if (chunk > 64) chunk = 64;

  dim3 blk(256);
  hipLaunchKernelGGL(wt_convert3, dim3(32, 32, 3), blk, 0, stream,
                     Wq, Wk, Wv, wtq, wtk, wtv);
  hipLaunchKernelGGL(er_convert, dim3(64), blk, 0, stream, Er, erb);

  dim3 gproj(DMODEL / 128, (BATCH * S_LEN) / 128, 3);  // (8, 32, 3)
  hipLaunchKernelGGL(proj_mfma3, gproj, blk, 0, stream,
                     q_in, k_in, v_in, wtq, wtk, wtv, bq, bk, bv, qp, kp, vp);

  for (int bh0 = 0; bh0 < BATCH * NHEADS; bh0 += chunk) {
    int nb = BATCH * NHEADS - bh0;
    if (nb > chunk) nb = chunk;
    dim3 gqer(S_LEN / 128, S_LEN / 128, nb);  // (8, 8, nb)
    hipLaunchKernelGGL(qer_mfma, gqer, blk, 0, stream, qp, erb, G, bh0);
    dim3 gattn(S_LEN / 64, nb);               // (16, nb)
    hipLaunchKernelGGL(attn_mfma, gattn, blk, 0, stream, qp, kp, vp, G, out, bh0);
  }
}

// Round 12
// 195.959 us; speedup vs baseline: 1.3418x; 1.2540x over previous
//
#include <hip/hip_runtime.h>
#include <hip/hip_bf16.h>
#include <cstdint>

#define S_LEN 1024
#define DMODEL 1024
#define NHEADS 16
#define DHEAD 64
#define MAXLEN 16384
#define BATCH 4

typedef __attribute__((ext_vector_type(8))) short bf16x8;
typedef __attribute__((ext_vector_type(4))) float f32x4;

// RNE f32 -> bf16 bits
__device__ inline unsigned short f2b(float f) {
  unsigned int u = __float_as_uint(f);
  unsigned int r = (u + 0x7FFFu + ((u >> 16) & 1u)) >> 16;
  return (unsigned short)r;
}
__device__ inline float b2f(unsigned short u) {
  return __uint_as_float(((unsigned int)u) << 16);
}

// Swizzled LDS element index for [R][64] bf16 rows (128B): 8 slots of 16B, slot ^= row&7.
#define LDSWZ(row, slot) (((row) << 6) + (((slot) ^ ((row) & 7)) << 3))

// ---------------- W transpose+convert x3: WT[n][k] bf16 = W[k][n] f32
__global__ __launch_bounds__(256) void wt_convert3(
    const float* __restrict__ W0, const float* __restrict__ W1, const float* __restrict__ W2,
    unsigned short* __restrict__ T0, unsigned short* __restrict__ T1, unsigned short* __restrict__ T2) {
  const float* W = (blockIdx.z == 0) ? W0 : (blockIdx.z == 1) ? W1 : W2;
  unsigned short* WT = (blockIdx.z == 0) ? T0 : (blockIdx.z == 1) ? T1 : T2;
  __shared__ float t[32][33];
  const int bi = blockIdx.y * 32, bj = blockIdx.x * 32;
  const int r = threadIdx.x >> 3, c4 = (threadIdx.x & 7) * 4;
  float4 f = *(const float4*)&W[(size_t)(bi + r) * DMODEL + bj + c4];
  t[r][c4] = f.x; t[r][c4 + 1] = f.y; t[r][c4 + 2] = f.z; t[r][c4 + 3] = f.w;
  __syncthreads();
  ushort4 u;
  u.x = f2b(t[c4][r]); u.y = f2b(t[c4 + 1][r]);
  u.z = f2b(t[c4 + 2][r]); u.w = f2b(t[c4 + 3][r]);
  *(ushort4*)&WT[(size_t)(bj + r) * DMODEL + bi + c4] = u;
}

// ---------------- Er slice convert: Erb[c][d] = bf16(Er[MAXLEN-S+c][d])
__global__ __launch_bounds__(256) void er_convert(const float* __restrict__ Er,
                                                  unsigned short* __restrict__ Erb) {
  const int i = blockIdx.x * 1024 + threadIdx.x * 4;
  float4 f = *(const float4*)(Er + (size_t)(MAXLEN - S_LEN) * DHEAD + i);
  Erb[i] = f2b(f.x); Erb[i + 1] = f2b(f.y); Erb[i + 2] = f2b(f.z); Erb[i + 3] = f2b(f.w);
}

// ---------------- Projections (z selects q/k/v): Out(bf16) = X@W + b
__global__ __launch_bounds__(256) void proj_mfma3(
    const float* __restrict__ X0, const float* __restrict__ X1, const float* __restrict__ X2,
    const unsigned short* __restrict__ T0, const unsigned short* __restrict__ T1,
    const unsigned short* __restrict__ T2,
    const float* __restrict__ b0, const float* __restrict__ b1, const float* __restrict__ b2,
    unsigned short* __restrict__ O0, unsigned short* __restrict__ O1,
    unsigned short* __restrict__ O2) {
  const int z = blockIdx.z;
  const float* X = (z == 0) ? X0 : (z == 1) ? X1 : X2;
  const unsigned short* WT = (z == 0) ? T0 : (z == 1) ? T1 : T2;
  const float* bias = (z == 0) ? b0 : (z == 1) ? b1 : b2;
  unsigned short* Out = (z == 0) ? O0 : (z == 1) ? O1 : O2;
  __shared__ unsigned short As[128 * 64];
  __shared__ unsigned short Bs[128 * 64];
  const int tid = threadIdx.x;
  const int l = tid & 63, wid = tid >> 6;
  const int bm = blockIdx.y * 128, bn = blockIdx.x * 128;
  const int wr = (wid >> 1) * 64, wc = (wid & 1) * 64;
  f32x4 acc[4][4] = {};
  for (int k0 = 0; k0 < DMODEL; k0 += 64) {
    __syncthreads();
#pragma unroll
    for (int r = 0; r < 4; ++r) {
      int s = r * 256 + tid;
      int row = s >> 3, sl = s & 7;
      const float* src = X + (size_t)(bm + row) * DMODEL + k0 + sl * 8;
      float4 f0 = *(const float4*)src;
      float4 f1 = *(const float4*)(src + 4);
      union { unsigned short h[8]; int4 v; } u;
      u.h[0] = f2b(f0.x); u.h[1] = f2b(f0.y); u.h[2] = f2b(f0.z); u.h[3] = f2b(f0.w);
      u.h[4] = f2b(f1.x); u.h[5] = f2b(f1.y); u.h[6] = f2b(f1.z); u.h[7] = f2b(f1.w);
      *(int4*)&As[LDSWZ(row, sl)] = u.v;
    }
#pragma unroll
    for (int r = 0; r < 4; ++r) {
      int s = r * 256 + tid;
      int row = s >> 3, sl = s & 7;
      int4 v = *(const int4*)(WT + (size_t)(bn + row) * DMODEL + k0 + sl * 8);
      *(int4*)&Bs[LDSWZ(row, sl)] = v;
    }
    __syncthreads();
#pragma unroll
    for (int ks = 0; ks < 2; ++ks) {
      bf16x8 a[4], b[4];
#pragma unroll
      for (int f = 0; f < 4; ++f) {
        int row = wr + f * 16 + (l & 15);
        a[f] = *(const bf16x8*)&As[LDSWZ(row, ks * 4 + (l >> 4))];
        int col = wc + f * 16 + (l & 15);
        b[f] = *(const bf16x8*)&Bs[LDSWZ(col, ks * 4 + (l >> 4))];
      }
#pragma unroll
      for (int i = 0; i < 4; ++i)
#pragma unroll
        for (int j = 0; j < 4; ++j)
          acc[i][j] = __builtin_amdgcn_mfma_f32_16x16x32_bf16(a[i], b[j], acc[i][j], 0, 0, 0);
    }
  }
#pragma unroll
  for (int i = 0; i < 4; ++i) {
    int m = bm + wr + i * 16 + ((l >> 4) << 2);
#pragma unroll
    for (int j = 0; j < 4; ++j) {
      int n = bn + wc + j * 16 + (l & 15);
      float bv = bias[n];
#pragma unroll
      for (int e = 0; e < 4; ++e)
        Out[(size_t)(m + e) * DMODEL + n] = f2b(acc[i][j][e] + bv);
    }
  }
}

// ---------------- Diagonal zero: Gsk[s][s+1] = 0 (the only cells qer never writes).
__global__ __launch_bounds__(256) void g_diag_zero(unsigned short* __restrict__ G) {
  int s = blockIdx.x * 256 + threadIdx.x;
  if (s < S_LEN - 1)
    G[(size_t)blockIdx.y * S_LEN * S_LEN + (size_t)s * S_LEN + s + 1] = 0;
}

// ---------------- QEr with PRE-SKEWED scatter: Gsk[s][t] = Srel[s][t].
// Raw value G[s][c] = q_s . Er_c maps to exactly one Srel cell:
//   c >= 1023-s -> Gsk[s][c+s-1023] ; else -> Gsk[s-1][c+s+1] (dropped if s==0).
// Same 4-row x 32B-contiguous store pattern as before (only index math changes).
__global__ __launch_bounds__(256) void qer_mfma(const unsigned short* __restrict__ qp,
    const unsigned short* __restrict__ Erb, unsigned short* __restrict__ G, int bh0) {
  const int bh = bh0 + blockIdx.z;
  const int b = bh >> 4, h = bh & 15;
  __shared__ unsigned short As[128 * 64];
  __shared__ unsigned short Bs[128 * 64];
  const int tid = threadIdx.x, l = tid & 63, wid = tid >> 6;
  const int bm = blockIdx.y * 128, bn = blockIdx.x * 128;
  const int wr = (wid >> 1) * 64, wc = (wid & 1) * 64;
  const unsigned short* qb = qp + (size_t)b * S_LEN * DMODEL + h * DHEAD;
  unsigned short* Gc = G + (size_t)blockIdx.z * S_LEN * S_LEN;
#pragma unroll
  for (int r = 0; r < 4; ++r) {
    int s = r * 256 + tid;
    int row = s >> 3, sl = s & 7;
    *(int4*)&As[LDSWZ(row, sl)] = *(const int4*)(qb + (size_t)(bm + row) * DMODEL + sl * 8);
    *(int4*)&Bs[LDSWZ(row, sl)] = *(const int4*)(Erb + (size_t)(bn + row) * DHEAD + sl * 8);
  }
  __syncthreads();
  f32x4 acc[4][4] = {};
#pragma unroll
  for (int ks = 0; ks < 2; ++ks) {
    bf16x8 a[4], b[4];
#pragma unroll
    for (int f = 0; f < 4; ++f) {
      int row = wr + f * 16 + (l & 15);
      a[f] = *(const bf16x8*)&As[LDSWZ(row, ks * 4 + (l >> 4))];
      int col = wc + f * 16 + (l & 15);
      b[f] = *(const bf16x8*)&Bs[LDSWZ(col, ks * 4 + (l >> 4))];
    }
#pragma unroll
    for (int i = 0; i < 4; ++i)
#pragma unroll
      for (int j = 0; j < 4; ++j)
        acc[i][j] = __builtin_amdgcn_mfma_f32_16x16x32_bf16(a[i], b[j], acc[i][j], 0, 0, 0);
  }
#pragma unroll
  for (int i = 0; i < 4; ++i) {
    int m = bm + wr + i * 16 + ((l >> 4) << 2);
#pragma unroll
    for (int j = 0; j < 4; ++j) {
      int n = bn + wc + j * 16 + (l & 15);
#pragma unroll
      for (int e = 0; e < 4; ++e) {
        int s = m + e;
        int hi = (n >= 1023 - s);
        int r_ = hi ? s : s - 1;
        int t_ = hi ? (n + s - 1023) : (n + s + 1);
        if (r_ >= 0)
          Gc[(size_t)r_ * S_LEN + t_] = f2b(acc[i][j][e]);
      }
    }
  }
}

// ---------------- Fused attention, r4 schedule (empirical best) + skewed-G gather.
// rel(s,t) = Gsk[s][t] -- branch-free, contiguous in t; diagonal already zero.
__global__ __launch_bounds__(256) void attn_skew(const unsigned short* __restrict__ qp,
    const unsigned short* __restrict__ kp, const unsigned short* __restrict__ vp,
    const unsigned short* __restrict__ G, float* __restrict__ out, int bh0) {
  const int bh = bh0 + blockIdx.y;
  const int b = bh >> 4, h = bh & 15;
  const int s0 = blockIdx.x * 64;
  __shared__ unsigned short Qs[64 * 64];
  __shared__ unsigned short Ks[64 * 64];
  __shared__ unsigned short Vt[64 * 64];   // [dh][t], pair-packed + swizzled
  __shared__ unsigned short Ps[4][16 * 64];
  const int tid = threadIdx.x, l = tid & 63, w = tid >> 6;
  const int lg = l >> 4, li = l & 15;
  const unsigned short* qb = qp + (size_t)b * S_LEN * DMODEL + h * DHEAD;
  const unsigned short* kb = kp + (size_t)b * S_LEN * DMODEL + h * DHEAD;
  const unsigned short* vb = vp + (size_t)b * S_LEN * DMODEL + h * DHEAD;
  const unsigned short* Gb = G + (size_t)blockIdx.y * S_LEN * S_LEN;

#pragma unroll
  for (int r = 0; r < 2; ++r) {  // stage Q 64x64
    int s = r * 256 + tid;
    int row = s >> 3, sl = s & 7;
    *(int4*)&Qs[LDSWZ(row, sl)] = *(const int4*)(qb + (size_t)(s0 + row) * DMODEL + sl * 8);
  }
  __syncthreads();
  bf16x8 qf[2];
#pragma unroll
  for (int ks = 0; ks < 2; ++ks)
    qf[ks] = *(const bf16x8*)&Qs[LDSWZ(w * 16 + li, ks * 4 + lg)];

  f32x4 o4[4] = {};
  float m_r[4] = {-1e30f, -1e30f, -1e30f, -1e30f};
  float l_r[4] = {0.f, 0.f, 0.f, 0.f};
  int sg[4];
  const unsigned short* gp[4];   // per-row gather base (contiguous in t), +li lane offset
#pragma unroll
  for (int i = 0; i < 4; ++i) {
    sg[i] = s0 + w * 16 + (lg << 2) + i;
    gp[i] = Gb + (size_t)sg[i] * S_LEN + li;
  }
  const int pr = tid & 31, dh0 = (tid >> 5) * 8;

  for (int ti = 0; ti < 16; ++ti) {
    const int t0 = ti * 64;
    __syncthreads();  // prev tile's Ks/Vt/Ps readers done
#pragma unroll
    for (int i2 = 0; i2 < 16; ++i2) { }  // (no-op; keep structure minimal)
#pragma unroll
    for (int r = 0; r < 2; ++r) {  // stage K tile (inline global->LDS, as r4)
      int s = r * 256 + tid; int row = s >> 3, sl = s & 7;
      *(int4*)&Ks[LDSWZ(row, sl)] = *(const int4*)(kb + (size_t)(t0 + row) * DMODEL + sl * 8);
    }
    {  // stage V transposed ([dh][t] pair-packed words)
      const unsigned short* v0p = vb + (size_t)(t0 + pr * 2) * DMODEL + dh0;
      union { int4 v; unsigned short hh[8]; } va, vc;
      va.v = *(const int4*)v0p;
      vc.v = *(const int4*)(v0p + DMODEL);
      unsigned int* vtw = (unsigned int*)Vt;
#pragma unroll
      for (int j = 0; j < 8; ++j) {
        int dh = dh0 + j;
        int widx = dh * 32 + (((pr >> 2) ^ (dh & 7)) << 2) + (pr & 3);
        vtw[widx] = (unsigned int)va.hh[j] | ((unsigned int)vc.hh[j] << 16);
      }
    }
    __syncthreads();  // K/V visible
    // --- issue rel gathers (branch-free addresses; covered by QK below)
    unsigned short rv[4][4];
#pragma unroll
    for (int f = 0; f < 4; ++f)
#pragma unroll
      for (int i = 0; i < 4; ++i)
        rv[f][i] = gp[i][t0 + f * 16];
    // --- QK^T
    f32x4 sa[4] = {};
#pragma unroll
    for (int ks = 0; ks < 2; ++ks)
#pragma unroll
      for (int f = 0; f < 4; ++f) {
        bf16x8 kf = *(const bf16x8*)&Ks[LDSWZ(f * 16 + li, ks * 4 + lg)];
        sa[f] = __builtin_amdgcn_mfma_f32_16x16x32_bf16(qf[ks], kf, sa[f], 0, 0, 0);
      }
    // --- apply rel (no branches, diagonal pre-zeroed) + scale + tile max
    float tmax[4] = {-1e30f, -1e30f, -1e30f, -1e30f};
#pragma unroll
    for (int f = 0; f < 4; ++f) {
#pragma unroll
      for (int i = 0; i < 4; ++i) {
        float sv = (sa[f][i] + b2f(rv[f][i])) * 0.125f;
        sa[f][i] = sv;
        tmax[i] = fmaxf(tmax[i], sv);
      }
    }
#pragma unroll
    for (int off = 8; off >= 1; off >>= 1)
#pragma unroll
      for (int i = 0; i < 4; ++i) tmax[i] = fmaxf(tmax[i], __shfl_xor(tmax[i], off));
    float scale[4];
#pragma unroll
    for (int i = 0; i < 4; ++i) {
      float mn = fmaxf(m_r[i], tmax[i]);
      scale[i] = __expf(m_r[i] - mn);
      m_r[i] = mn;
    }
    // --- P = exp(s-m), bf16 strip per wave, row sums
    float psum[4] = {0.f, 0.f, 0.f, 0.f};
    unsigned short* Pw = &Ps[w][0];
#pragma unroll
    for (int f = 0; f < 4; ++f) {
#pragma unroll
      for (int i = 0; i < 4; ++i) {
        float pv = __expf(sa[f][i] - m_r[i]);
        psum[i] += pv;
        int prow = (lg << 2) + i, pcol = f * 16 + li;
        Pw[LDSWZ(prow, pcol >> 3) + (pcol & 7)] = f2b(pv);
      }
    }
#pragma unroll
    for (int off = 8; off >= 1; off >>= 1)
#pragma unroll
      for (int i = 0; i < 4; ++i) psum[i] += __shfl_xor(psum[i], off);
#pragma unroll
    for (int i = 0; i < 4; ++i) l_r[i] = l_r[i] * scale[i] + psum[i];
#pragma unroll
    for (int f = 0; f < 4; ++f)
#pragma unroll
      for (int i = 0; i < 4; ++i) o4[f][i] *= scale[i];
    // --- PV
#pragma unroll
    for (int ks = 0; ks < 2; ++ks) {
      bf16x8 pf = *(const bf16x8*)&Pw[LDSWZ(li, ks * 4 + lg)];
#pragma unroll
      for (int f = 0; f < 4; ++f) {
        bf16x8 vf = *(const bf16x8*)&Vt[LDSWZ(f * 16 + li, ks * 4 + lg)];
        o4[f] = __builtin_amdgcn_mfma_f32_16x16x32_bf16(pf, vf, o4[f], 0, 0, 0);
      }
    }
  }
  // ---- epilogue
#pragma unroll
  for (int i = 0; i < 4; ++i) {
    float inv = 1.f / l_r[i];
#pragma unroll
    for (int f = 0; f < 4; ++f)
      out[(size_t)(b * S_LEN + sg[i]) * DMODEL + h * DHEAD + f * 16 + li] = o4[f][i] * inv;
  }
}

extern "C" void kernel_launch(void* const* d_in, const int* in_sizes, int n_in,
                              void* d_out, int out_size, void* d_ws, size_t ws_size,
                              hipStream_t stream) {
  (void)in_sizes; (void)n_in; (void)out_size;
  const float* q_in = (const float*)d_in[0];
  const float* k_in = (const float*)d_in[1];
  const float* v_in = (const float*)d_in[2];
  const float* Wq   = (const float*)d_in[3];
  const float* bq   = (const float*)d_in[4];
  const float* Wk   = (const float*)d_in[5];
  const float* bk   = (const float*)d_in[6];
  const float* Wv   = (const float*)d_in[7];
  const float* bv   = (const float*)d_in[8];
  const float* Er   = (const float*)d_in[9];
  float* out = (float*)d_out;

  char* ws = (char*)d_ws;
  const size_t MB = (size_t)1 << 20;
  unsigned short* wtq = (unsigned short*)(ws);            // 2 MB
  unsigned short* wtk = (unsigned short*)(ws + 2 * MB);   // 2 MB
  unsigned short* wtv = (unsigned short*)(ws + 4 * MB);   // 2 MB
  unsigned short* erb = (unsigned short*)(ws + 6 * MB);   // 128 KB
  unsigned short* qp  = (unsigned short*)(ws + 8 * MB);   // 8 MB
  unsigned short* kp  = (unsigned short*)(ws + 16 * MB);  // 8 MB
  unsigned short* vp  = (unsigned short*)(ws + 24 * MB);  // 8 MB
  unsigned short* G   = (unsigned short*)(ws + 32 * MB);  // nb * 2 MB

  const size_t gavail = (ws_size > 32 * MB) ? (ws_size - 32 * MB) : 0;
  int chunk = (int)(gavail / (2 * MB));
  if (chunk < 1) chunk = 1;
  if (chunk > 64) chunk = 64;

  dim3 blk(256);
  hipLaunchKernelGGL(wt_convert3, dim3(32, 32, 3), blk, 0, stream,
                     Wq, Wk, Wv, wtq, wtk, wtv);
  hipLaunchKernelGGL(er_convert, dim3(64), blk, 0, stream, Er, erb);

  dim3 gproj(DMODEL / 128, (BATCH * S_LEN) / 128, 3);  // (8, 32, 3)
  hipLaunchKernelGGL(proj_mfma3, gproj, blk, 0, stream,
                     q_in, k_in, v_in, wtq, wtk, wtv, bq, bk, bv, qp, kp, vp);

  for (int bh0 = 0; bh0 < BATCH * NHEADS; bh0 += chunk) {
    int nb = BATCH * NHEADS - bh0;
    if (nb > chunk) nb = chunk;
    hipLaunchKernelGGL(g_diag_zero, dim3(4, nb), blk, 0, stream, G);
    dim3 gqer(S_LEN / 128, S_LEN / 128, nb);  // (8, 8, nb)
    hipLaunchKernelGGL(qer_mfma, gqer, blk, 0, stream, qp, erb, G, bh0);
    dim3 gattn(S_LEN / 64, nb);               // (16, nb)
    hipLaunchKernelGGL(attn_skew, gattn, blk, 0, stream, qp, kp, vp, G, out, bh0);
  }
}

// Round 13
// 180.471 us; speedup vs baseline: 1.4569x; 1.0858x over previous
//
#include <hip/hip_runtime.h>
#include <hip/hip_bf16.h>
#include <cstdint>

#define S_LEN 1024
#define DMODEL 1024
#define NHEADS 16
#define DHEAD 64
#define MAXLEN 16384
#define BATCH 4

typedef __attribute__((ext_vector_type(8))) short bf16x8;
typedef __attribute__((ext_vector_type(4))) float f32x4;

#define AS1(p) ((const __attribute__((address_space(1))) unsigned int*)(p))
#define AS3(p) ((__attribute__((address_space(3))) unsigned int*)(p))

// RNE f32 -> bf16 bits
__device__ inline unsigned short f2b(float f) {
  unsigned int u = __float_as_uint(f);
  unsigned int r = (u + 0x7FFFu + ((u >> 16) & 1u)) >> 16;
  return (unsigned short)r;
}
__device__ inline float b2f(unsigned short u) {
  return __uint_as_float(((unsigned int)u) << 16);
}

// Swizzled LDS element index for [R][64] bf16 rows (128B): 8 slots of 16B, slot ^= row&7.
#define LDSWZ(row, slot) (((row) << 6) + (((slot) ^ ((row) & 7)) << 3))

// ---------------- W transpose+convert x3: WT[n][k] bf16 = W[k][n] f32
__global__ __launch_bounds__(256) void wt_convert3(
    const float* __restrict__ W0, const float* __restrict__ W1, const float* __restrict__ W2,
    unsigned short* __restrict__ T0, unsigned short* __restrict__ T1, unsigned short* __restrict__ T2) {
  const float* W = (blockIdx.z == 0) ? W0 : (blockIdx.z == 1) ? W1 : W2;
  unsigned short* WT = (blockIdx.z == 0) ? T0 : (blockIdx.z == 1) ? T1 : T2;
  __shared__ float t[32][33];
  const int bi = blockIdx.y * 32, bj = blockIdx.x * 32;
  const int r = threadIdx.x >> 3, c4 = (threadIdx.x & 7) * 4;
  float4 f = *(const float4*)&W[(size_t)(bi + r) * DMODEL + bj + c4];
  t[r][c4] = f.x; t[r][c4 + 1] = f.y; t[r][c4 + 2] = f.z; t[r][c4 + 3] = f.w;
  __syncthreads();
  ushort4 u;
  u.x = f2b(t[c4][r]); u.y = f2b(t[c4 + 1][r]);
  u.z = f2b(t[c4 + 2][r]); u.w = f2b(t[c4 + 3][r]);
  *(ushort4*)&WT[(size_t)(bj + r) * DMODEL + bi + c4] = u;
}

// ---------------- X convert x3: Xb(bf16) = X(f32), flat stream, 16 elts/thread
__global__ __launch_bounds__(256) void xconvert3(
    const float* __restrict__ X0, const float* __restrict__ X1, const float* __restrict__ X2,
    unsigned short* __restrict__ B0, unsigned short* __restrict__ B1, unsigned short* __restrict__ B2) {
  const int z = blockIdx.z;
  const float* X = (z == 0) ? X0 : (z == 1) ? X1 : X2;
  unsigned short* B = (z == 0) ? B0 : (z == 1) ? B1 : B2;
  size_t i = ((size_t)blockIdx.x * 256 + threadIdx.x) * 16;
  union { unsigned short h[16]; int4 v[2]; } u;
#pragma unroll
  for (int r = 0; r < 4; ++r) {
    float4 f = *(const float4*)(X + i + r * 4);
    u.h[r * 4 + 0] = f2b(f.x); u.h[r * 4 + 1] = f2b(f.y);
    u.h[r * 4 + 2] = f2b(f.z); u.h[r * 4 + 3] = f2b(f.w);
  }
  *(int4*)(B + i) = u.v[0];
  *(int4*)(B + i + 8) = u.v[1];
}

// ---------------- Er slice convert: Erb[c][d] = bf16(Er[MAXLEN-S+c][d])
__global__ __launch_bounds__(256) void er_convert(const float* __restrict__ Er,
                                                  unsigned short* __restrict__ Erb) {
  const int i = blockIdx.x * 1024 + threadIdx.x * 4;
  float4 f = *(const float4*)(Er + (size_t)(MAXLEN - S_LEN) * DHEAD + i);
  Erb[i] = f2b(f.x); Erb[i + 1] = f2b(f.y); Erb[i + 2] = f2b(f.z); Erb[i + 3] = f2b(f.w);
}

// ---------------- Projections, m97 structure: global_load_lds(16B) staging with
// pre-swizzled SOURCE addresses (LDS written linearly -> effective swizzled layout),
// XCD-aware grid remap (each XCD: 4 M-panels + 8 N-panels = 3 MB, L2-resident).
__global__ __launch_bounds__(256) void proj_glds3(
    const unsigned short* __restrict__ Xq, const unsigned short* __restrict__ Xk,
    const unsigned short* __restrict__ Xv,
    const unsigned short* __restrict__ T0, const unsigned short* __restrict__ T1,
    const unsigned short* __restrict__ T2,
    const float* __restrict__ b0, const float* __restrict__ b1, const float* __restrict__ b2,
    unsigned short* __restrict__ O0, unsigned short* __restrict__ O1,
    unsigned short* __restrict__ O2) {
  const int z = blockIdx.z;
  const unsigned short* X = (z == 0) ? Xq : (z == 1) ? Xk : Xv;
  const unsigned short* WT = (z == 0) ? T0 : (z == 1) ? T1 : T2;
  const float* bias = (z == 0) ? b0 : (z == 1) ? b1 : b2;
  unsigned short* Out = (z == 0) ? O0 : (z == 1) ? O1 : O2;
  __shared__ unsigned short As[128 * 64];
  __shared__ unsigned short Bs[128 * 64];
  const int tid = threadIdx.x;
  const int l = tid & 63, w = tid >> 6;
  // XCD remap within the 256-block z-slice: lid = (o&7)*32 + (o>>3)
  const int o = blockIdx.y * 8 + blockIdx.x;
  const int lid = (o & 7) * 32 + (o >> 3);
  const int bm = (lid >> 3) * 128, bn = (lid & 7) * 128;
  const int wr = (w >> 1) * 64, wc = (w & 1) * 64;
  // staging source pre-swizzle: lane l covers (row = base8 + l>>3, phys slot = l&7);
  // content must be global slot (l&7)^(row&7); row&7 == (l>>3)&7 since base8 % 8 == 0.
  const int lrow = l >> 3;
  const int slotlog = (l & 7) ^ (lrow & 7);
  const unsigned short* Xa = X + (size_t)(bm + lrow) * DMODEL + slotlog * 8;
  const unsigned short* Wa = WT + (size_t)(bn + lrow) * DMODEL + slotlog * 8;
  f32x4 acc[4][4] = {};
  for (int k0 = 0; k0 < DMODEL; k0 += 64) {
    __syncthreads();  // readers of prev tile done
#pragma unroll
    for (int j = 0; j < 4; ++j) {
      int r8 = (w * 4 + j) * 8;  // 8-row group staged by this issue
      __builtin_amdgcn_global_load_lds(AS1(Xa + (size_t)r8 * DMODEL + k0),
                                       AS3(&As[(w * 4 + j) * 512]), 16, 0, 0);
      __builtin_amdgcn_global_load_lds(AS1(Wa + (size_t)r8 * DMODEL + k0),
                                       AS3(&Bs[(w * 4 + j) * 512]), 16, 0, 0);
    }
    __syncthreads();  // vmcnt(0) drain -> staged tile visible
#pragma unroll
    for (int ks = 0; ks < 2; ++ks) {
      bf16x8 a[4], b[4];
#pragma unroll
      for (int f = 0; f < 4; ++f) {
        int row = wr + f * 16 + (l & 15);
        a[f] = *(const bf16x8*)&As[LDSWZ(row, ks * 4 + (l >> 4))];
        int col = wc + f * 16 + (l & 15);
        b[f] = *(const bf16x8*)&Bs[LDSWZ(col, ks * 4 + (l >> 4))];
      }
#pragma unroll
      for (int i = 0; i < 4; ++i)
#pragma unroll
        for (int j = 0; j < 4; ++j)
          acc[i][j] = __builtin_amdgcn_mfma_f32_16x16x32_bf16(a[i], b[j], acc[i][j], 0, 0, 0);
    }
  }
#pragma unroll
  for (int i = 0; i < 4; ++i) {
    int m = bm + wr + i * 16 + ((l >> 4) << 2);
#pragma unroll
    for (int j = 0; j < 4; ++j) {
      int n = bn + wc + j * 16 + (l & 15);
      float bv = bias[n];
#pragma unroll
      for (int e = 0; e < 4; ++e)
        Out[(size_t)(m + e) * DMODEL + n] = f2b(acc[i][j][e] + bv);
    }
  }
}

// ---------------- Diagonal zero: Gsk[s][s+1] = 0 (the only cells qer never writes).
__global__ __launch_bounds__(256) void g_diag_zero(unsigned short* __restrict__ G) {
  int s = blockIdx.x * 256 + threadIdx.x;
  if (s < S_LEN - 1)
    G[(size_t)blockIdx.y * S_LEN * S_LEN + (size_t)s * S_LEN + s + 1] = 0;
}

// ---------------- QEr with PRE-SKEWED scatter: Gsk[s][t] = Srel[s][t].
//   c >= 1023-s -> Gsk[s][c+s-1023] ; else -> Gsk[s-1][c+s+1] (dropped if s==0).
__global__ __launch_bounds__(256) void qer_mfma(const unsigned short* __restrict__ qp,
    const unsigned short* __restrict__ Erb, unsigned short* __restrict__ G, int bh0) {
  const int bh = bh0 + blockIdx.z;
  const int b = bh >> 4, h = bh & 15;
  __shared__ unsigned short As[128 * 64];
  __shared__ unsigned short Bs[128 * 64];
  const int tid = threadIdx.x, l = tid & 63, wid = tid >> 6;
  const int bm = blockIdx.y * 128, bn = blockIdx.x * 128;
  const int wr = (wid >> 1) * 64, wc = (wid & 1) * 64;
  const unsigned short* qb = qp + (size_t)b * S_LEN * DMODEL + h * DHEAD;
  unsigned short* Gc = G + (size_t)blockIdx.z * S_LEN * S_LEN;
#pragma unroll
  for (int r = 0; r < 4; ++r) {
    int s = r * 256 + tid;
    int row = s >> 3, sl = s & 7;
    *(int4*)&As[LDSWZ(row, sl)] = *(const int4*)(qb + (size_t)(bm + row) * DMODEL + sl * 8);
    *(int4*)&Bs[LDSWZ(row, sl)] = *(const int4*)(Erb + (size_t)(bn + row) * DHEAD + sl * 8);
  }
  __syncthreads();
  f32x4 acc[4][4] = {};
#pragma unroll
  for (int ks = 0; ks < 2; ++ks) {
    bf16x8 a[4], b[4];
#pragma unroll
    for (int f = 0; f < 4; ++f) {
      int row = wr + f * 16 + (l & 15);
      a[f] = *(const bf16x8*)&As[LDSWZ(row, ks * 4 + (l >> 4))];
      int col = wc + f * 16 + (l & 15);
      b[f] = *(const bf16x8*)&Bs[LDSWZ(col, ks * 4 + (l >> 4))];
    }
#pragma unroll
    for (int i = 0; i < 4; ++i)
#pragma unroll
      for (int j = 0; j < 4; ++j)
        acc[i][j] = __builtin_amdgcn_mfma_f32_16x16x32_bf16(a[i], b[j], acc[i][j], 0, 0, 0);
  }
#pragma unroll
  for (int i = 0; i < 4; ++i) {
    int m = bm + wr + i * 16 + ((l >> 4) << 2);
#pragma unroll
    for (int j = 0; j < 4; ++j) {
      int n = bn + wc + j * 16 + (l & 15);
#pragma unroll
      for (int e = 0; e < 4; ++e) {
        int s = m + e;
        int hi = (n >= 1023 - s);
        int r_ = hi ? s : s - 1;
        int t_ = hi ? (n + s - 1023) : (n + s + 1);
        if (r_ >= 0)
          Gc[(size_t)r_ * S_LEN + t_] = f2b(acc[i][j][e]);
      }
    }
  }
}

// ---------------- Fused attention, r4 schedule + skewed-G gather (branch-free rel).
__global__ __launch_bounds__(256) void attn_skew(const unsigned short* __restrict__ qp,
    const unsigned short* __restrict__ kp, const unsigned short* __restrict__ vp,
    const unsigned short* __restrict__ G, float* __restrict__ out, int bh0) {
  const int bh = bh0 + blockIdx.y;
  const int b = bh >> 4, h = bh & 15;
  const int s0 = blockIdx.x * 64;
  __shared__ unsigned short Qs[64 * 64];
  __shared__ unsigned short Ks[64 * 64];
  __shared__ unsigned short Vt[64 * 64];
  __shared__ unsigned short Ps[4][16 * 64];
  const int tid = threadIdx.x, l = tid & 63, w = tid >> 6;
  const int lg = l >> 4, li = l & 15;
  const unsigned short* qb = qp + (size_t)b * S_LEN * DMODEL + h * DHEAD;
  const unsigned short* kb = kp + (size_t)b * S_LEN * DMODEL + h * DHEAD;
  const unsigned short* vb = vp + (size_t)b * S_LEN * DMODEL + h * DHEAD;
  const unsigned short* Gb = G + (size_t)blockIdx.y * S_LEN * S_LEN;

#pragma unroll
  for (int r = 0; r < 2; ++r) {
    int s = r * 256 + tid;
    int row = s >> 3, sl = s & 7;
    *(int4*)&Qs[LDSWZ(row, sl)] = *(const int4*)(qb + (size_t)(s0 + row) * DMODEL + sl * 8);
  }
  __syncthreads();
  bf16x8 qf[2];
#pragma unroll
  for (int ks = 0; ks < 2; ++ks)
    qf[ks] = *(const bf16x8*)&Qs[LDSWZ(w * 16 + li, ks * 4 + lg)];

  f32x4 o4[4] = {};
  float m_r[4] = {-1e30f, -1e30f, -1e30f, -1e30f};
  float l_r[4] = {0.f, 0.f, 0.f, 0.f};
  int sg[4];
  const unsigned short* gp[4];
#pragma unroll
  for (int i = 0; i < 4; ++i) {
    sg[i] = s0 + w * 16 + (lg << 2) + i;
    gp[i] = Gb + (size_t)sg[i] * S_LEN + li;
  }
  const int pr = tid & 31, dh0 = (tid >> 5) * 8;

  for (int ti = 0; ti < 16; ++ti) {
    const int t0 = ti * 64;
    __syncthreads();
#pragma unroll
    for (int r = 0; r < 2; ++r) {
      int s = r * 256 + tid; int row = s >> 3, sl = s & 7;
      *(int4*)&Ks[LDSWZ(row, sl)] = *(const int4*)(kb + (size_t)(t0 + row) * DMODEL + sl * 8);
    }
    {
      const unsigned short* v0p = vb + (size_t)(t0 + pr * 2) * DMODEL + dh0;
      union { int4 v; unsigned short hh[8]; } va, vc;
      va.v = *(const int4*)v0p;
      vc.v = *(const int4*)(v0p + DMODEL);
      unsigned int* vtw = (unsigned int*)Vt;
#pragma unroll
      for (int j = 0; j < 8; ++j) {
        int dh = dh0 + j;
        int widx = dh * 32 + (((pr >> 2) ^ (dh & 7)) << 2) + (pr & 3);
        vtw[widx] = (unsigned int)va.hh[j] | ((unsigned int)vc.hh[j] << 16);
      }
    }
    __syncthreads();
    unsigned short rv[4][4];
#pragma unroll
    for (int f = 0; f < 4; ++f)
#pragma unroll
      for (int i = 0; i < 4; ++i)
        rv[f][i] = gp[i][t0 + f * 16];
    f32x4 sa[4] = {};
#pragma unroll
    for (int ks = 0; ks < 2; ++ks)
#pragma unroll
      for (int f = 0; f < 4; ++f) {
        bf16x8 kf = *(const bf16x8*)&Ks[LDSWZ(f * 16 + li, ks * 4 + lg)];
        sa[f] = __builtin_amdgcn_mfma_f32_16x16x32_bf16(qf[ks], kf, sa[f], 0, 0, 0);
      }
    float tmax[4] = {-1e30f, -1e30f, -1e30f, -1e30f};
#pragma unroll
    for (int f = 0; f < 4; ++f) {
#pragma unroll
      for (int i = 0; i < 4; ++i) {
        float sv = (sa[f][i] + b2f(rv[f][i])) * 0.125f;
        sa[f][i] = sv;
        tmax[i] = fmaxf(tmax[i], sv);
      }
    }
#pragma unroll
    for (int off = 8; off >= 1; off >>= 1)
#pragma unroll
      for (int i = 0; i < 4; ++i) tmax[i] = fmaxf(tmax[i], __shfl_xor(tmax[i], off));
    float scale[4];
#pragma unroll
    for (int i = 0; i < 4; ++i) {
      float mn = fmaxf(m_r[i], tmax[i]);
      scale[i] = __expf(m_r[i] - mn);
      m_r[i] = mn;
    }
    float psum[4] = {0.f, 0.f, 0.f, 0.f};
    unsigned short* Pw = &Ps[w][0];
#pragma unroll
    for (int f = 0; f < 4; ++f) {
#pragma unroll
      for (int i = 0; i < 4; ++i) {
        float pv = __expf(sa[f][i] - m_r[i]);
        psum[i] += pv;
        int prow = (lg << 2) + i, pcol = f * 16 + li;
        Pw[LDSWZ(prow, pcol >> 3) + (pcol & 7)] = f2b(pv);
      }
    }
#pragma unroll
    for (int off = 8; off >= 1; off >>= 1)
#pragma unroll
      for (int i = 0; i < 4; ++i) psum[i] += __shfl_xor(psum[i], off);
#pragma unroll
    for (int i = 0; i < 4; ++i) l_r[i] = l_r[i] * scale[i] + psum[i];
#pragma unroll
    for (int f = 0; f < 4; ++f)
#pragma unroll
      for (int i = 0; i < 4; ++i) o4[f][i] *= scale[i];
#pragma unroll
    for (int ks = 0; ks < 2; ++ks) {
      bf16x8 pf = *(const bf16x8*)&Pw[LDSWZ(li, ks * 4 + lg)];
#pragma unroll
      for (int f = 0; f < 4; ++f) {
        bf16x8 vf = *(const bf16x8*)&Vt[LDSWZ(f * 16 + li, ks * 4 + lg)];
        o4[f] = __builtin_amdgcn_mfma_f32_16x16x32_bf16(pf, vf, o4[f], 0, 0, 0);
      }
    }
  }
#pragma unroll
  for (int i = 0; i < 4; ++i) {
    float inv = 1.f / l_r[i];
#pragma unroll
    for (int f = 0; f < 4; ++f)
      out[(size_t)(b * S_LEN + sg[i]) * DMODEL + h * DHEAD + f * 16 + li] = o4[f][i] * inv;
  }
}

extern "C" void kernel_launch(void* const* d_in, const int* in_sizes, int n_in,
                              void* d_out, int out_size, void* d_ws, size_t ws_size,
                              hipStream_t stream) {
  (void)in_sizes; (void)n_in; (void)out_size;
  const float* q_in = (const float*)d_in[0];
  const float* k_in = (const float*)d_in[1];
  const float* v_in = (const float*)d_in[2];
  const float* Wq   = (const float*)d_in[3];
  const float* bq   = (const float*)d_in[4];
  const float* Wk   = (const float*)d_in[5];
  const float* bk   = (const float*)d_in[6];
  const float* Wv   = (const float*)d_in[7];
  const float* bv   = (const float*)d_in[8];
  const float* Er   = (const float*)d_in[9];
  float* out = (float*)d_out;

  char* ws = (char*)d_ws;
  const size_t MB = (size_t)1 << 20;
  unsigned short* wtq = (unsigned short*)(ws);            // 2 MB
  unsigned short* wtk = (unsigned short*)(ws + 2 * MB);   // 2 MB
  unsigned short* wtv = (unsigned short*)(ws + 4 * MB);   // 2 MB
  unsigned short* erb = (unsigned short*)(ws + 6 * MB);   // 128 KB
  unsigned short* qp  = (unsigned short*)(ws + 8 * MB);   // 8 MB
  unsigned short* kp  = (unsigned short*)(ws + 16 * MB);  // 8 MB
  unsigned short* vp  = (unsigned short*)(ws + 24 * MB);  // 8 MB
  unsigned short* xq  = (unsigned short*)(ws + 32 * MB);  // 8 MB (bf16 X)
  unsigned short* xk  = (unsigned short*)(ws + 40 * MB);  // 8 MB
  unsigned short* xv  = (unsigned short*)(ws + 48 * MB);  // 8 MB
  unsigned short* G   = (unsigned short*)(ws + 56 * MB);  // nb * 2 MB

  const size_t gavail = (ws_size > 56 * MB) ? (ws_size - 56 * MB) : 0;
  int chunk = (int)(gavail / (2 * MB));
  if (chunk < 1) chunk = 1;
  if (chunk > 64) chunk = 64;

  dim3 blk(256);
  hipLaunchKernelGGL(wt_convert3, dim3(32, 32, 3), blk, 0, stream,
                     Wq, Wk, Wv, wtq, wtk, wtv);
  hipLaunchKernelGGL(xconvert3, dim3(1024, 1, 3), blk, 0, stream,
                     q_in, k_in, v_in, xq, xk, xv);
  hipLaunchKernelGGL(er_convert, dim3(64), blk, 0, stream, Er, erb);

  dim3 gproj(DMODEL / 128, (BATCH * S_LEN) / 128, 3);  // (8, 32, 3)
  hipLaunchKernelGGL(proj_glds3, gproj, blk, 0, stream,
                     xq, xk, xv, wtq, wtk, wtv, bq, bk, bv, qp, kp, vp);

  for (int bh0 = 0; bh0 < BATCH * NHEADS; bh0 += chunk) {
    int nb = BATCH * NHEADS - bh0;
    if (nb > chunk) nb = chunk;
    hipLaunchKernelGGL(g_diag_zero, dim3(4, nb), blk, 0, stream, G);
    dim3 gqer(S_LEN / 128, S_LEN / 128, nb);  // (8, 8, nb)
    hipLaunchKernelGGL(qer_mfma, gqer, blk, 0, stream, qp, erb, G, bh0);
    dim3 gattn(S_LEN / 64, nb);               // (16, nb)
    hipLaunchKernelGGL(attn_skew, gattn, blk, 0, stream, qp, kp, vp, G, out, bh0);
  }
}